// Round 9
// baseline (8588.393 us; speedup 1.0000x reference)
//
#include <hip/hip_runtime.h>
#include <hip/hip_bf16.h>
#include <stdint.h>

#define BB 64
#define TT 512
#define DD 512
#define UU 1024
#define G4 4096
#define RETRY_CAP 8192

typedef __bf16 bf16x8 __attribute__((ext_vector_type(8)));
typedef float f32x4 __attribute__((ext_vector_type(4)));
typedef int i32x4 __attribute__((ext_vector_type(4)));
typedef unsigned int u32;
typedef unsigned short u16;
typedef u16 u16x8 __attribute__((ext_vector_type(8)));

__device__ __forceinline__ u16 f2bf(float f) {
  unsigned u = __builtin_bit_cast(unsigned, f);
  return (u16)((u + 0x7FFFu + ((u >> 16) & 1u)) >> 16);  // RTN-even
}

// ---- x f32 -> bf16, same [B][T][D] layout, 8 elems/thread ----
__global__ void cvt_x_kernel(const float* __restrict__ x, u16* __restrict__ xb, int n8) {
  int i = blockIdx.x * blockDim.x + threadIdx.x;
  if (i >= n8) return;
  const float4* p = reinterpret_cast<const float4*>(x) + (size_t)i * 2;
  float4 a = p[0], b = p[1];
  u16x8 o;
  o[0] = f2bf(a.x); o[1] = f2bf(a.y); o[2] = f2bf(a.z); o[3] = f2bf(a.w);
  o[4] = f2bf(b.x); o[5] = f2bf(b.y); o[6] = f2bf(b.z); o[7] = f2bf(b.w);
  reinterpret_cast<u16x8*>(xb)[i] = o;
}

// zero hbuf tags with write-through (sc0 sc1) -- R2/R7-proven access type
__global__ void zero_kernel(u32* __restrict__ p, int nwords) {
  for (int i = blockIdx.x * blockDim.x + threadIdx.x; i < nwords; i += gridDim.x * blockDim.x) {
    u32 z = 0u;
    const u32* q = p + i;
    asm volatile("global_store_dword %0, %1, off sc0 sc1" :: "v"(q), "v"(z) : "memory");
  }
}

// ---- persistent LSTM, 4-way batch-group rotation to hide visibility latency ----
// 64 WGs x 256 thr (4 waves), 1 wave/SIMD (waves_per_eu(1,1)) => 64 WGs on 64
// CUs, always co-resident (64 <= 256; pure blockIdx partition, no XCD
// assumptions). WG bid owns u [bid*16,+16) for ALL 4 groups; group g = batch
// rows [g*16,+16) -- independent recurrences processed in rotation, so group
// g's h (stored at rotation slot g) has a full super-step (~3 groups' compute)
// to become visible before it is consumed -> retries ~0.
// Transport = R7-proven: tagged u32 ((bf16<<16)|t), sc0 sc1 both sides,
// fire-and-forget stores, per-dword atomic self-validation, double buffer.
// Waves k-split: x [w*128,+128), h [w*256,+256). Weights in registers
// (~330 VGPR; 1 wave/SIMD gives 512 budget -- no spills).
__launch_bounds__(256, 1) __attribute__((amdgpu_waves_per_eu(1, 1)))
__global__ void lstm_persist(const float* __restrict__ W, const float* __restrict__ R,
                             const float* __restrict__ bias, const u16* __restrict__ xb,
                             u32* __restrict__ hbuf,  // [4 grp][2 buf][16 row][1024 u] u32
                             float* __restrict__ out) {
  __shared__ float zone[4 * 4 * 64 * 4];  // [w][f][lane][reg] f32, 16 KB

  const int bid = blockIdx.x;      // 0..63
  const int tid = threadIdx.x;
  const int w = tid >> 6, lane = tid & 63, l15 = lane & 15, lk = lane >> 4;
  const int u0 = bid * 16;
  const int r = tid >> 4;          // 0..15 gate-phase row
  const int uu = tid & 15;         // gate-phase u

  // ---- persistent weight fragments (R2-verified layout) ----
  bf16x8 Wf[4][4];  // [s][g]: k0 = w*128 + s*32 + lk*8
  bf16x8 Rf[8][4];  // [s][g]: k0 = w*256 + s*32 + lk*8
  #pragma unroll
  for (int g = 0; g < 4; ++g) {
    const int gcol = g * 1024 + u0 + l15;
    #pragma unroll
    for (int s = 0; s < 4; ++s) {
      const int k0 = w * 128 + s * 32 + lk * 8;
      u16x8 tmp;
      #pragma unroll
      for (int j = 0; j < 8; ++j) tmp[j] = f2bf(W[(size_t)(k0 + j) * G4 + gcol]);
      Wf[s][g] = __builtin_bit_cast(bf16x8, tmp);
    }
    #pragma unroll
    for (int s = 0; s < 8; ++s) {
      const int k0 = w * 256 + s * 32 + lk * 8;
      u16x8 tmp;
      #pragma unroll
      for (int j = 0; j < 8; ++j) tmp[j] = f2bf(R[(size_t)(k0 + j) * G4 + gcol]);
      Rf[s][g] = __builtin_bit_cast(bf16x8, tmp);
    }
  }
  float bv[4];
  #pragma unroll
  for (int g = 0; g < 4; ++g) bv[g] = bias[g * 1024 + u0 + uu];
  float cst[4] = {0.f, 0.f, 0.f, 0.f};  // per-group cell state for (r, u0+uu)

  // ---- pointers (layout elem = (g*32 + parity*16 + row)*1024 + u) ----
  const u16* xq[4];
  const u32* hr[4];
  u32* hs[4];
  #pragma unroll
  for (int g = 0; g < 4; ++g) {
    xq[g] = xb + (size_t)(g * 16 + l15) * (TT * DD) + w * 128 + lk * 8;
    hr[g] = hbuf + (size_t)(g * 32 + l15) * 1024 + w * 256 + lk * 8;
    hs[g] = hbuf + (size_t)(g * 32 + r) * 1024 + u0 + uu;
  }

  asm volatile("s_waitcnt vmcnt(0)" ::: "memory");  // weight loads drained
  __builtin_amdgcn_sched_barrier(0);

  i32x4 H[8][2], Ax[4];
  f32x4 acc[4];

#define HISSUE(HQ)                                                             \
  asm volatile(                                                                \
      "global_load_dwordx4 %0, %16, off sc0 sc1\n\t"                           \
      "global_load_dwordx4 %1, %16, off offset:16 sc0 sc1\n\t"                 \
      "global_load_dwordx4 %2, %16, off offset:128 sc0 sc1\n\t"                \
      "global_load_dwordx4 %3, %16, off offset:144 sc0 sc1\n\t"                \
      "global_load_dwordx4 %4, %16, off offset:256 sc0 sc1\n\t"                \
      "global_load_dwordx4 %5, %16, off offset:272 sc0 sc1\n\t"                \
      "global_load_dwordx4 %6, %16, off offset:384 sc0 sc1\n\t"                \
      "global_load_dwordx4 %7, %16, off offset:400 sc0 sc1\n\t"                \
      "global_load_dwordx4 %8, %16, off offset:512 sc0 sc1\n\t"                \
      "global_load_dwordx4 %9, %16, off offset:528 sc0 sc1\n\t"                \
      "global_load_dwordx4 %10, %16, off offset:640 sc0 sc1\n\t"               \
      "global_load_dwordx4 %11, %16, off offset:656 sc0 sc1\n\t"               \
      "global_load_dwordx4 %12, %16, off offset:768 sc0 sc1\n\t"               \
      "global_load_dwordx4 %13, %16, off offset:784 sc0 sc1\n\t"               \
      "global_load_dwordx4 %14, %16, off offset:896 sc0 sc1\n\t"               \
      "global_load_dwordx4 %15, %16, off offset:912 sc0 sc1"                   \
      : "=&v"(H[0][0]), "=&v"(H[0][1]), "=&v"(H[1][0]), "=&v"(H[1][1]),        \
        "=&v"(H[2][0]), "=&v"(H[2][1]), "=&v"(H[3][0]), "=&v"(H[3][1]),        \
        "=&v"(H[4][0]), "=&v"(H[4][1]), "=&v"(H[5][0]), "=&v"(H[5][1]),        \
        "=&v"(H[6][0]), "=&v"(H[6][1]), "=&v"(H[7][0]), "=&v"(H[7][1])         \
      : "v"(HQ) : "memory")

#define VBAD(badv)                                                             \
  badv = 0;                                                                    \
  _Pragma("unroll") for (int s_ = 0; s_ < 8; ++s_)                             \
    _Pragma("unroll") for (int q_ = 0; q_ < 2; ++q_)                           \
      _Pragma("unroll") for (int d_ = 0; d_ < 4; ++d_)                         \
        badv |= (H[s_][q_][d_] ^ t) & 0xFFFF

  #pragma unroll 1
  for (int t = 0; t < TT; ++t) {
    const int pr = (t & 1) * 16384;        // read-buffer word offset
    const int pw = ((t + 1) & 1) * 16384;  // write-buffer word offset

    #pragma unroll
    for (int g = 0; g < 4; ++g) {
      // issue x A-loads (plain cached)
      asm volatile(
          "global_load_dwordx4 %0, %4, off\n\t"
          "global_load_dwordx4 %1, %4, off offset:64\n\t"
          "global_load_dwordx4 %2, %4, off offset:128\n\t"
          "global_load_dwordx4 %3, %4, off offset:192"
          : "=&v"(Ax[0]), "=&v"(Ax[1]), "=&v"(Ax[2]), "=&v"(Ax[3])
          : "v"(xq[g]));
      xq[g] += DD;

      const u32* hq = hr[g] + pr;
      if (t > 0) {
        HISSUE(hq);  // speculative; stored one full super-step ago -> likely ready
        asm volatile("s_waitcnt vmcnt(16)" ::: "memory");  // x (and older stores) done
      } else {
        asm volatile("s_waitcnt vmcnt(0)" ::: "memory");
      }
      __builtin_amdgcn_sched_barrier(0);

      #pragma unroll
      for (int f = 0; f < 4; ++f) acc[f] = f32x4{0.f, 0.f, 0.f, 0.f};

      // x-part MFMA
      #pragma unroll
      for (int s = 0; s < 4; ++s)
        #pragma unroll
        for (int f = 0; f < 4; ++f)
          acc[f] = __builtin_amdgcn_mfma_f32_16x16x32_bf16(
              __builtin_bit_cast(bf16x8, Ax[s]), Wf[s][f], acc[f], 0, 0, 0);

      if (t > 0) {
        asm volatile("s_waitcnt vmcnt(0)" ::: "memory");
        __builtin_amdgcn_sched_barrier(0);
        int bad;
        VBAD(bad);
        int rtry = 0;
        while (__any(bad != 0) && ++rtry < RETRY_CAP) {
          __builtin_amdgcn_s_sleep(2);  // backoff: don't hammer the IC
          HISSUE(hq);
          asm volatile("s_waitcnt vmcnt(0)" ::: "memory");
          __builtin_amdgcn_sched_barrier(0);
          VBAD(bad);
        }
        // h-part MFMA (extract hi16 payload via v_perm; R7-verified)
        #pragma unroll
        for (int s = 0; s < 8; ++s) {
          i32x4 fr;
          fr[0] = __builtin_amdgcn_perm(H[s][0][1], H[s][0][0], 0x07060302);
          fr[1] = __builtin_amdgcn_perm(H[s][0][3], H[s][0][2], 0x07060302);
          fr[2] = __builtin_amdgcn_perm(H[s][1][1], H[s][1][0], 0x07060302);
          fr[3] = __builtin_amdgcn_perm(H[s][1][3], H[s][1][2], 0x07060302);
          #pragma unroll
          for (int f = 0; f < 4; ++f)
            acc[f] = __builtin_amdgcn_mfma_f32_16x16x32_bf16(
                __builtin_bit_cast(bf16x8, fr), Rf[s][f], acc[f], 0, 0, 0);
        }
      }

      // ---- k-split exchange through LDS ----
      __syncthreads();  // WAR vs previous group's zone reads
      #pragma unroll
      for (int f = 0; f < 4; ++f)
        *(f32x4*)&zone[((w * 4 + f) * 64 + lane) * 4] = acc[f];
      __syncthreads();

      // ---- gates: thread owns (row=r, u=u0+uu) of group g ----
      float z[4];
      #pragma unroll
      for (int gg = 0; gg < 4; ++gg) {
        float s = bv[gg];
        #pragma unroll
        for (int ww = 0; ww < 4; ++ww)
          s += zone[((ww * 4 + gg) * 64 + (r >> 2) * 16 + uu) * 4 + (r & 3)];
        z[gg] = s;
      }
      const float ig = 1.f / (1.f + __expf(-z[0]));
      const float fg = 1.f / (1.f + __expf(-z[1]));
      const float gt = 1.f - 2.f / (1.f + __expf(2.f * z[2]));  // tanh, inf-safe
      const float og = 1.f / (1.f + __expf(-z[3]));
      const float c = fg * cst[g] + ig * gt;
      cst[g] = c;
      const float h = og * (1.f - 2.f / (1.f + __expf(2.f * c)));

      if (t < TT - 1) {
        const u32 hwd = ((u32)f2bf(h) << 16) | (u32)(t + 1);
        u32* hp = hs[g] + pw;
        asm volatile("global_store_dword %0, %1, off sc0 sc1" :: "v"(hp), "v"(hwd) : "memory");
        // fire-and-forget: tag self-validates at consumers
      } else {
        out[(size_t)(g * 16 + r) * UU + u0 + uu] = h;
      }
    }
  }
#undef HISSUE
#undef VBAD
}

extern "C" void kernel_launch(void* const* d_in, const int* in_sizes, int n_in,
                              void* d_out, int out_size, void* d_ws, size_t ws_size,
                              hipStream_t stream) {
  const float* x = (const float*)d_in[0];
  const float* W = (const float*)d_in[1];
  const float* R = (const float*)d_in[2];
  const float* b = (const float*)d_in[3];
  float* out = (float*)d_out;

  char* ws = (char*)d_ws;
  u16* xb = (u16*)ws;                                // 32 MB
  const size_t XB_BYTES = (size_t)BB * TT * DD * 2;
  u32* hbuf = (u32*)(ws + XB_BYTES);                 // 4*2*16*1024*4 = 512 KB
  const int HB_WORDS = 4 * 2 * 16 * 1024;

  hipLaunchKernelGGL(cvt_x_kernel, dim3((BB * TT * DD / 8 + 255) / 256), dim3(256), 0, stream,
                     x, xb, BB * TT * DD / 8);
  hipLaunchKernelGGL(zero_kernel, dim3(64), dim3(256), 0, stream, hbuf, HB_WORDS);
  hipLaunchKernelGGL(lstm_persist, dim3(64), dim3(256), 0, stream,
                     W, R, b, xb, hbuf, out);
}

// Round 10
// 5180.046 us; speedup vs baseline: 1.6580x; 1.6580x over previous
//
#include <hip/hip_runtime.h>
#include <hip/hip_bf16.h>
#include <stdint.h>

#define BB 64
#define TT 512
#define DD 512
#define UU 1024
#define G4 4096
#define RETRY_CAP 4096

typedef __bf16 bf16x8 __attribute__((ext_vector_type(8)));
typedef float f32x4 __attribute__((ext_vector_type(4)));
typedef int i32x4 __attribute__((ext_vector_type(4)));
typedef unsigned int u32;
typedef unsigned short u16;
typedef u16 u16x8 __attribute__((ext_vector_type(8)));

__device__ __forceinline__ u16 f2bf(float f) {
  unsigned u = __builtin_bit_cast(unsigned, f);
  return (u16)((u + 0x7FFFu + ((u >> 16) & 1u)) >> 16);  // RTN-even
}

__global__ void cvt_x_kernel(const float* __restrict__ x, u16* __restrict__ xb, int n8) {
  int i = blockIdx.x * blockDim.x + threadIdx.x;
  if (i >= n8) return;
  const float4* p = reinterpret_cast<const float4*>(x) + (size_t)i * 2;
  float4 a = p[0], b = p[1];
  u16x8 o;
  o[0] = f2bf(a.x); o[1] = f2bf(a.y); o[2] = f2bf(a.z); o[3] = f2bf(a.w);
  o[4] = f2bf(b.x); o[5] = f2bf(b.y); o[6] = f2bf(b.z); o[7] = f2bf(b.w);
  reinterpret_cast<u16x8*>(xb)[i] = o;
}

__global__ void zero_kernel(u32* __restrict__ p, int nwords) {
  for (int i = blockIdx.x * blockDim.x + threadIdx.x; i < nwords; i += gridDim.x * blockDim.x) {
    u32 z = 0u;
    const u32* q = p + i;
    asm volatile("global_store_dword %0, %1, off sc0 sc1" :: "v"(q), "v"(z) : "memory");
  }
}

// ---- persistent LSTM: 4-group rotation + cross-slot prefetch pipeline ----
// 64 WGs x 512 thr (8 waves). WG owns u [bid*16,+16) for all 4 groups
// (16 batch rows each). Slot j = t*4+g. Pipeline: at slot j issue x(j+1),
// wait vmcnt(11) (drains h-target(j) issued at slot j-2 and x(j) issued at
// slot j-1 -- FIFO-counted), compute, then issue h(j+2) into the freed bank.
// Transport R7-proven: tagged u32 ((bf16<<16)|t), sc0 sc1, fire-and-forget,
// validate+retry. W in LDS (swizzled); Rf in regs; ~215 VGPR, no spill.
__launch_bounds__(512, 1)
__global__ void lstm_persist(const float* __restrict__ W, const float* __restrict__ R,
                             const float* __restrict__ bias, const u16* __restrict__ xb,
                             u32* __restrict__ hbuf,  // [4 grp][2 buf][16 row][1024 u] u32
                             float* __restrict__ out) {
  __shared__ u16 Wlds[64 * 512];          // 64 KB, [col][k] bf16, XOR-swizzled
  __shared__ float zone[8 * 4 * 64 * 4];  // 32 KB: [wave][gate][lane][comp]

  const int tid = threadIdx.x;
  const int w = tid >> 6, lane = tid & 63, l15 = lane & 15, lk = lane >> 4;
  const int u0 = blockIdx.x * 16;
  const int gr = w * 2 + ((lane >> 4) & 1);  // gate row 0..15 (lanes<32)
  const int guu = lane & 15;
  const bool gact = lane < 32;

  // ---- stage W slice (512 k x 64 cols) into LDS ----
  {
    const int c = tid & 63;                       // col = g*16 + uc
    const int gcol = (c >> 4) * 1024 + u0 + (c & 15);
    const int kbase = (tid >> 6) * 64;
    for (int kk = 0; kk < 64; ++kk) {
      const int k = kbase + kk;
      const unsigned byte = ((unsigned)(c * 1024 + k * 2)) ^ ((unsigned)((c & 7) << 4));
      *(u16*)((char*)Wlds + byte) = f2bf(W[(size_t)k * G4 + gcol]);
    }
  }

  // ---- persistent R fragments: wave w owns h-k [w*128,+128) ----
  bf16x8 Rf[4][4];  // [s][g]
  #pragma unroll
  for (int g = 0; g < 4; ++g) {
    const int gcol = g * 1024 + u0 + l15;
    #pragma unroll
    for (int s = 0; s < 4; ++s) {
      const int k0 = w * 128 + s * 32 + lk * 8;
      u16x8 tmp;
      #pragma unroll
      for (int j = 0; j < 8; ++j) tmp[j] = f2bf(R[(size_t)(k0 + j) * G4 + gcol]);
      Rf[s][g] = __builtin_bit_cast(bf16x8, tmp);
    }
  }
  float bv[4];
  #pragma unroll
  for (int g = 0; g < 4; ++g) bv[g] = bias[g * 1024 + u0 + guu];
  float cst[4] = {0.f, 0.f, 0.f, 0.f};

  // ---- pointers ----
  const u16* xq[4];
  const u32* hrb[4];
  u32* hsb[4];
  #pragma unroll
  for (int g = 0; g < 4; ++g) {
    xq[g] = xb + (size_t)(g * 16 + l15) * (TT * DD) + w * 64 + lk * 8;
    hrb[g] = hbuf + (size_t)(g * 32 + l15) * 1024 + w * 128 + lk * 8;
    hsb[g] = hbuf + (size_t)(g * 32 + gr) * 1024 + u0 + guu;
  }

  __syncthreads();
  asm volatile("s_waitcnt vmcnt(0) lgkmcnt(0)" ::: "memory");
  __builtin_amdgcn_sched_barrier(0);

  i32x4 HA[8], HB[8];    // h banks (slot parity g&1)
  i32x4 AxA[2], AxB[2];  // x banks

#define XPREF(AX, GN)                                                    \
  asm volatile(                                                          \
      "global_load_dwordx4 %0, %2, off\n\t"                              \
      "global_load_dwordx4 %1, %2, off offset:64"                        \
      : "=&v"(AX[0]), "=&v"(AX[1]) : "v"(xq[GN]));                       \
  xq[GN] += DD

#define HISSUE(HB_, HP)                                                  \
  asm volatile(                                                          \
      "global_load_dwordx4 %0, %8, off sc0 sc1\n\t"                      \
      "global_load_dwordx4 %1, %8, off offset:16 sc0 sc1\n\t"            \
      "global_load_dwordx4 %2, %8, off offset:128 sc0 sc1\n\t"           \
      "global_load_dwordx4 %3, %8, off offset:144 sc0 sc1\n\t"           \
      "global_load_dwordx4 %4, %8, off offset:256 sc0 sc1\n\t"           \
      "global_load_dwordx4 %5, %8, off offset:272 sc0 sc1\n\t"           \
      "global_load_dwordx4 %6, %8, off offset:384 sc0 sc1\n\t"           \
      "global_load_dwordx4 %7, %8, off offset:400 sc0 sc1"               \
      : "=&v"(HB_[0]), "=&v"(HB_[1]), "=&v"(HB_[2]), "=&v"(HB_[3]),      \
        "=&v"(HB_[4]), "=&v"(HB_[5]), "=&v"(HB_[6]), "=&v"(HB_[7])       \
      : "v"(HP) : "memory")

#define VBAD(HB_, badv)                                                  \
  badv = 0;                                                              \
  _Pragma("unroll") for (int i_ = 0; i_ < 8; ++i_)                       \
    _Pragma("unroll") for (int d_ = 0; d_ < 4; ++d_)                     \
      badv |= (HB_[i_][d_] ^ t) & 0xFFFF

  // prime x for slot 0
  XPREF(AxA, 0);

  #pragma unroll 1
  for (int t = 0; t < TT; ++t) {
    const int pr = (t & 1) * 16384;        // consume-parity word offset
    const int pw = ((t + 1) & 1) * 16384;  // store-parity word offset

#define SLOT(G, AXC, AXP, HBK)                                                     \
  {                                                                                \
    XPREF(AXP, (G + 1) & 3);                        /* x for slot j+1 */           \
    if ((G) == 0 && t == 0) { asm volatile("s_waitcnt vmcnt(2)" ::: "memory"); }   \
    else                    { asm volatile("s_waitcnt vmcnt(11)" ::: "memory"); }  \
    __builtin_amdgcn_sched_barrier(0);                                             \
    f32x4 acc[4];                                                                  \
    _Pragma("unroll") for (int g_ = 0; g_ < 4; ++g_) acc[g_] = f32x4{0,0,0,0};     \
    _Pragma("unroll") for (int s_ = 0; s_ < 2; ++s_) {                             \
      _Pragma("unroll") for (int g_ = 0; g_ < 4; ++g_) {                           \
        const int c_ = g_ * 16 + l15;                                              \
        const unsigned byte_ = ((unsigned)(c_ * 1024 + (w * 64 + s_ * 32 + lk * 8) * 2)) \
                               ^ ((unsigned)((c_ & 7) << 4));                      \
        bf16x8 wfr_ = *(const bf16x8*)((const char*)Wlds + byte_);                 \
        acc[g_] = __builtin_amdgcn_mfma_f32_16x16x32_bf16(                         \
            __builtin_bit_cast(bf16x8, AXC[s_]), wfr_, acc[g_], 0, 0, 0);          \
      }                                                                            \
    }                                                                              \
    if (t > 0) {                                                                   \
      int bad_;                                                                    \
      VBAD(HBK, bad_);                                                             \
      int rtry_ = 0;                                                               \
      while (__any(bad_ != 0) && ++rtry_ < RETRY_CAP) {                            \
        __builtin_amdgcn_s_sleep(1);                                               \
        HISSUE(HBK, hrb[G] + pr);                                                  \
        asm volatile("s_waitcnt vmcnt(0)" ::: "memory");                           \
        __builtin_amdgcn_sched_barrier(0);                                         \
        VBAD(HBK, bad_);                                                           \
      }                                                                            \
      _Pragma("unroll") for (int s_ = 0; s_ < 4; ++s_) {                           \
        i32x4 fr_;                                                                 \
        fr_[0] = __builtin_amdgcn_perm(HBK[2*s_][1],   HBK[2*s_][0],   0x07060302);\
        fr_[1] = __builtin_amdgcn_perm(HBK[2*s_][3],   HBK[2*s_][2],   0x07060302);\
        fr_[2] = __builtin_amdgcn_perm(HBK[2*s_+1][1], HBK[2*s_+1][0], 0x07060302);\
        fr_[3] = __builtin_amdgcn_perm(HBK[2*s_+1][3], HBK[2*s_+1][2], 0x07060302);\
        _Pragma("unroll") for (int g_ = 0; g_ < 4; ++g_)                           \
          acc[g_] = __builtin_amdgcn_mfma_f32_16x16x32_bf16(                       \
              __builtin_bit_cast(bf16x8, fr_), Rf[s_][g_], acc[g_], 0, 0, 0);      \
      }                                                                            \
    }                                                                              \
    /* prefetch h for slot j+2 into the just-freed bank */                         \
    {                                                                              \
      const int gc_ = (G + 2) & 3;                                                 \
      const int pc_ = ((G) >= 2) ? (((t + 1) & 1) * 16384) : pr;                   \
      HISSUE(HBK, hrb[gc_] + pc_);                                                 \
    }                                                                              \
    __syncthreads();                                                               \
    _Pragma("unroll") for (int g_ = 0; g_ < 4; ++g_)                               \
      *(f32x4*)&zone[((w * 4 + g_) * 64 + lane) * 4] = acc[g_];                    \
    __syncthreads();                                                               \
    if (gact) {                                                                    \
      const int lsrc_ = (gr >> 2) * 16 + guu, jj_ = gr & 3;                        \
      float z_[4];                                                                 \
      _Pragma("unroll") for (int g_ = 0; g_ < 4; ++g_) {                           \
        float s_ = bv[g_];                                                         \
        _Pragma("unroll") for (int ww_ = 0; ww_ < 8; ++ww_)                        \
          s_ += zone[((ww_ * 4 + g_) * 64 + lsrc_) * 4 + jj_];                     \
        z_[g_] = s_;                                                               \
      }                                                                            \
      const float ig_ = 1.f / (1.f + __expf(-z_[0]));                              \
      const float fg_ = 1.f / (1.f + __expf(-z_[1]));                              \
      const float gt_ = 1.f - 2.f / (1.f + __expf(2.f * z_[2]));                   \
      const float og_ = 1.f / (1.f + __expf(-z_[3]));                              \
      const float c_ = fg_ * cst[G] + ig_ * gt_;                                   \
      cst[G] = c_;                                                                 \
      const float h_ = og_ * (1.f - 2.f / (1.f + __expf(2.f * c_)));               \
      if (t < TT - 1) {                                                            \
        const u32 hw_ = ((u32)f2bf(h_) << 16) | (u32)(t + 1);                      \
        u32* hp_ = hsb[G] + pw;                                                    \
        asm volatile("global_store_dword %0, %1, off sc0 sc1"                      \
                     :: "v"(hp_), "v"(hw_) : "memory");                            \
      } else {                                                                     \
        out[(size_t)((G) * 16 + gr) * UU + u0 + guu] = h_;                         \
      }                                                                            \
    }                                                                              \
  }

    SLOT(0, AxA, AxB, HA)
    SLOT(1, AxB, AxA, HB)
    SLOT(2, AxA, AxB, HA)
    SLOT(3, AxB, AxA, HB)
#undef SLOT
  }
#undef XPREF
#undef HISSUE
#undef VBAD
}

extern "C" void kernel_launch(void* const* d_in, const int* in_sizes, int n_in,
                              void* d_out, int out_size, void* d_ws, size_t ws_size,
                              hipStream_t stream) {
  const float* x = (const float*)d_in[0];
  const float* W = (const float*)d_in[1];
  const float* R = (const float*)d_in[2];
  const float* b = (const float*)d_in[3];
  float* out = (float*)d_out;

  char* ws = (char*)d_ws;
  u16* xb = (u16*)ws;                                // 32 MB
  const size_t XB_BYTES = (size_t)BB * TT * DD * 2;
  u32* hbuf = (u32*)(ws + XB_BYTES);                 // 4*2*16*1024*4 = 512 KB
  const int HB_WORDS = 4 * 2 * 16 * 1024;

  hipLaunchKernelGGL(cvt_x_kernel, dim3((BB * TT * DD / 8 + 255) / 256), dim3(256), 0, stream,
                     x, xb, BB * TT * DD / 8);
  hipLaunchKernelGGL(zero_kernel, dim3(64), dim3(256), 0, stream, hbuf, HB_WORDS);
  hipLaunchKernelGGL(lstm_persist, dim3(64), dim3(512), 0, stream,
                     W, R, b, xb, hbuf, out);
}